// Round 14
// baseline (243.925 us; speedup 1.0000x reference)
//
#include <hip/hip_runtime.h>
#include <hip/hip_fp16.h>
#include <hip/hip_bf16.h>
#include <math.h>

// GAT 2-layer forward, MI355X. FP32 in/out, int32 edge_index.
// R14: gemm1/gemm2 process 4 node-tiles per block (weight staging amortized
// 4x, grid/4). All else from R13 (proven): scan-free scatter, fused build,
// MFMA gemms with folded att columns, 4-node/wave latency-optimized aggs.

#define LRELU(v) ((v) > 0.f ? (v) : 0.2f * (v))
#define BSH 8            // 256 nodes per bucket
#define BCAP 5120        // staged capacity per bucket
#define CHK 8192         // edges per k_scatter block
#define CAP1 64          // agg1 LDS edge cache per node
#define CAP2 64          // agg2 LDS edge cache per node

typedef __attribute__((ext_vector_type(8))) short short8;
typedef __attribute__((ext_vector_type(8))) _Float16 half8;
typedef __attribute__((ext_vector_type(4))) float float4v;

static __device__ __forceinline__ short f2bf(float f) {
    __hip_bfloat16 b = __float2bfloat16(f);
    return *reinterpret_cast<short*>(&b);
}

// Pass 1 (scan-free): histogram -> reserve per-bucket global runs -> direct
// writes into contiguous runs.
__global__ __launch_bounds__(256) void k_scatter(const int* __restrict__ ei, int* __restrict__ cursor,
                                                 int* __restrict__ stage, int E, int NBK) {
    __shared__ int hist[512];
    __shared__ int cnt2[512];
    __shared__ int base[512];
    int tid = threadIdx.x;
    int e0 = blockIdx.x * CHK;
    int nedge = E - e0; if (nedge > CHK) nedge = CHK;

    for (int i = tid; i < 512; i += 256) { hist[i] = 0; cnt2[i] = 0; }
    __syncthreads();
    for (int j = tid; j < nedge; j += 256) {
        int d = ei[E + e0 + j];
        atomicAdd(&hist[d >> BSH], 1);
    }
    __syncthreads();
    for (int b = tid; b < NBK; b += 256) {
        int c = hist[b];
        if (c > 0) base[b] = b * BCAP + atomicAdd(&cursor[b], c);
    }
    __syncthreads();
    for (int j = tid; j < nedge; j += 256) {
        int s = ei[e0 + j];
        int d = ei[E + e0 + j];
        int b = d >> BSH;
        int r = atomicAdd(&cnt2[b], 1);
        stage[base[b] + r] = s | ((d & ((1 << BSH) - 1)) << 17);
    }
}

// Pass 2: per-bucket fine CSR build; block 0 adds row_start[N], Wc, Wc2.
__global__ __launch_bounds__(256) void k_build(const int* __restrict__ stage,
                                               const int* __restrict__ cursor,
                                               int* __restrict__ row_start,
                                               int* __restrict__ csr,
                                               const float* __restrict__ W1,
                                               const float* __restrict__ att_src,
                                               const float* __restrict__ att_dst,
                                               float* __restrict__ Wc,
                                               const float* __restrict__ W2,
                                               const float* __restrict__ att_src2,
                                               const float* __restrict__ att_dst2,
                                               float* __restrict__ Wc2,
                                               int NBK, int E, int N) {
    __shared__ int cnt[256];
    __shared__ int lb[256];
    __shared__ int cur[256];
    __shared__ int sA[256];
    int b = blockIdx.x, tid = threadIdx.x;
    int nodes0 = b << BSH;
    int nnodes = N - nodes0; if (nnodes > 256) nnodes = 256;
    int partial = 0;
    for (int i = tid; i < b; i += 256) partial += cursor[i];
    sA[tid] = partial;
    __syncthreads();
    for (int off = 128; off >= 1; off >>= 1) {
        if (tid < off) sA[tid] += sA[tid + off];
        __syncthreads();
    }
    int ebase = sA[0];
    int ecnt = cursor[b];
    __syncthreads();
    if (b == 0) {
        if (tid == 0) row_start[N] = E + N;
        for (int i = tid; i < 16 * 128; i += 256) {
            int col = i >> 7, k = i & 127;
            float v = 0.f;
            if (col < 8) {
                int h = col & 3;
                const float* att = (col < 4) ? att_src : att_dst;
                #pragma unroll
                for (int c = 0; c < 16; c++) v += W1[k * 64 + h * 16 + c] * att[h * 16 + c];
            }
            Wc[i] = v;
        }
        for (int i = tid; i < 128; i += 256) {
            int col = i >> 6, k = i & 63;
            const float* att = col ? att_dst2 : att_src2;
            float v = 0.f;
            #pragma unroll
            for (int c = 0; c < 16; c++) v += W2[k * 16 + c] * att[c];
            Wc2[i] = v;
        }
    }
    const int* sbk = stage + b * BCAP;
    cnt[tid] = (tid < nnodes) ? 1 : 0;  // self loop
    __syncthreads();
    for (int e = tid; e < ecnt; e += 256) {
        int l = (sbk[e] >> 17) & 255;
        atomicAdd(&cnt[l], 1);
    }
    __syncthreads();
    int myc = cnt[tid];
    sA[tid] = myc;
    __syncthreads();
    for (int off = 1; off < 256; off <<= 1) {
        int r = sA[tid] + ((tid >= off) ? sA[tid - off] : 0);
        __syncthreads();
        sA[tid] = r;
        __syncthreads();
    }
    int gb = ebase + nodes0;
    lb[tid] = sA[tid] - myc;
    cur[tid] = 1;
    __syncthreads();
    if (tid < nnodes) {
        row_start[nodes0 + tid] = gb + lb[tid];
        csr[gb + lb[tid]] = nodes0 + tid;
    }
    __syncthreads();
    for (int e = tid; e < ecnt; e += 256) {
        int v = sbk[e];
        int l = (v >> 17) & 255;
        int src = v & 0x1FFFF;
        int r = atomicAdd(&cur[l], 1);
        csr[gb + lb[l] + r] = src;
    }
}

// h1[N,64](fp16) = x[N,128] @ W1[128,64] via MFMA 16x16x32 bf16.
// 4 node-tiles per block: weight staging amortized 4x.
__global__ __launch_bounds__(256) void k_gemm1(const float* __restrict__ x,
                                               const float* __restrict__ W1,
                                               const float* __restrict__ Wc,
                                               __half* __restrict__ h1, float* __restrict__ a_src,
                                               float* __restrict__ a_dst, int N) {
    __shared__ short wt[80 * 136];   // cols 0-63: W1^T; cols 64-79: Wc
    int tid = threadIdx.x;
    for (int i = tid; i < 128 * 64; i += 256) {
        int k = i >> 6, c = i & 63;
        wt[c * 136 + k] = f2bf(W1[i]);
    }
    for (int i = tid; i < 16 * 128; i += 256) {
        int col = i >> 7, k = i & 127;
        wt[(64 + col) * 136 + k] = f2bf(Wc[i]);
    }
    __syncthreads();
    int wave = tid >> 6, lane = tid & 63;
    int m = lane & 15, q = lane >> 4;

    #pragma unroll
    for (int t = 0; t < 4; t++) {
        int nbase = blockIdx.x * 256 + t * 64 + wave * 16;
        if (nbase >= N) break;
        int anode = nbase + m;
        bool rowok = anode < N;
        const float* xrow = x + (size_t)(rowok ? anode : 0) * 128 + q * 8;

        float4v acc[5];
        #pragma unroll
        for (int ct = 0; ct < 5; ct++)
            #pragma unroll
            for (int r = 0; r < 4; r++) acc[ct][r] = 0.f;

        #pragma unroll
        for (int kc = 0; kc < 4; kc++) {
            float4 u0 = make_float4(0.f, 0.f, 0.f, 0.f), u1 = u0;
            if (rowok) {
                u0 = *(const float4*)(xrow + kc * 32);
                u1 = *(const float4*)(xrow + kc * 32 + 4);
            }
            short8 af;
            af[0] = f2bf(u0.x); af[1] = f2bf(u0.y); af[2] = f2bf(u0.z); af[3] = f2bf(u0.w);
            af[4] = f2bf(u1.x); af[5] = f2bf(u1.y); af[6] = f2bf(u1.z); af[7] = f2bf(u1.w);
            #pragma unroll
            for (int ct = 0; ct < 5; ct++) {
                short8 bf = *(const short8*)&wt[(ct * 16 + m) * 136 + kc * 32 + q * 8];
                acc[ct] = __builtin_amdgcn_mfma_f32_16x16x32_bf16(af, bf, acc[ct], 0, 0, 0);
            }
        }
        #pragma unroll
        for (int ct = 0; ct < 4; ct++) {
            #pragma unroll
            for (int r = 0; r < 4; r++) {
                int n = nbase + q * 4 + r;
                if (n < N) h1[(size_t)n * 64 + ct * 16 + m] = __float2half(acc[ct][r]);
            }
        }
        #pragma unroll
        for (int r = 0; r < 4; r++) {
            int n = nbase + q * 4 + r;
            if (n < N) {
                float v = acc[4][r];
                if (m < 4) a_src[n * 4 + m] = v;
                else if (m < 8) a_dst[n * 4 + (m - 4)] = v;
            }
        }
    }
}

// layer-1 aggregation: 4 nodes per wave (16 lanes x 4 channels); out1 fp16
__global__ __launch_bounds__(256) void k_agg1(const int* __restrict__ row_start,
                                              const int* __restrict__ csr_src,
                                              const float* __restrict__ a_src,
                                              const float* __restrict__ a_dst,
                                              const __half* __restrict__ h1,
                                              const float* __restrict__ bias,
                                              __half* __restrict__ out1, int N) {
    __shared__ int   sidx[16][CAP1];
    __shared__ float sval[16][CAP1 * 4];
    int tid = threadIdx.x;
    int wave = tid >> 6, lane = tid & 63;
    int quad = lane >> 4, l16 = lane & 15;
    int slot = wave * 4 + quad;
    int node = blockIdx.x * 16 + slot;
    if (node >= N) return;
    int row = row_start[node];
    int deg = row_start[node + 1] - row;
    float4 ad = ((const float4*)a_dst)[node];
    float s0 = 0.f, s1 = 0.f, s2 = 0.f, s3 = 0.f;
    for (int j = l16; j < deg; j += 16) {
        int s = csr_src[row + j];
        float4 as = ((const float4*)a_src)[s];
        float e0 = __expf(LRELU(as.x + ad.x));
        float e1 = __expf(LRELU(as.y + ad.y));
        float e2 = __expf(LRELU(as.z + ad.z));
        float e3 = __expf(LRELU(as.w + ad.w));
        if (j < CAP1) {
            sidx[slot][j] = s;
            *(float4*)&sval[slot][j * 4] = make_float4(e0, e1, e2, e3);
        }
        s0 += e0; s1 += e1; s2 += e2; s3 += e3;
    }
    #pragma unroll
    for (int m = 1; m < 16; m <<= 1) {
        s0 += __shfl_xor(s0, m, 64);
        s1 += __shfl_xor(s1, m, 64);
        s2 += __shfl_xor(s2, m, 64);
        s3 += __shfl_xor(s3, m, 64);
    }
    int myh = l16 >> 2;
    float ssv = myh == 0 ? s0 : myh == 1 ? s1 : myh == 2 ? s2 : s3;
    float adm = myh == 0 ? ad.x : myh == 1 ? ad.y : myh == 2 ? ad.z : ad.w;
    float iv = 1.f / (ssv + 1e-16f);
    float A0 = 0.f, A1 = 0.f, A2 = 0.f, A3 = 0.f;
    float B0 = 0.f, B1 = 0.f, B2 = 0.f, B3 = 0.f;
    int dc = deg < CAP1 ? deg : CAP1;
    int j = 0;
    for (; j + 8 <= dc; j += 8) {
        int t[8]; float e[8]; float2 lo[8], hi[8];
        #pragma unroll
        for (int u = 0; u < 8; u++) {
            t[u] = sidx[slot][j + u];
            e[u] = sval[slot][(j + u) * 4 + myh];
        }
        #pragma unroll
        for (int u = 0; u < 8; u++) {
            union { float2 f; __half2 h[2]; } uu;
            uu.f = *(const float2*)&h1[(size_t)t[u] * 64 + l16 * 4];
            lo[u] = __half22float2(uu.h[0]);
            hi[u] = __half22float2(uu.h[1]);
        }
        #pragma unroll
        for (int u = 0; u < 8; u += 2) {
            A0 += e[u] * lo[u].x; A1 += e[u] * lo[u].y;
            A2 += e[u] * hi[u].x; A3 += e[u] * hi[u].y;
            B0 += e[u + 1] * lo[u + 1].x; B1 += e[u + 1] * lo[u + 1].y;
            B2 += e[u + 1] * hi[u + 1].x; B3 += e[u + 1] * hi[u + 1].y;
        }
    }
    for (; j < dc; j++) {
        int t = sidx[slot][j];
        float e = sval[slot][j * 4 + myh];
        union { float2 f; __half2 h[2]; } uu;
        uu.f = *(const float2*)&h1[(size_t)t * 64 + l16 * 4];
        float2 lo = __half22float2(uu.h[0]), hi = __half22float2(uu.h[1]);
        A0 += e * lo.x; A1 += e * lo.y; A2 += e * hi.x; A3 += e * hi.y;
    }
    for (; j < deg; j++) {   // deg > CAP1 fallback
        int s = csr_src[row + j];
        float e = __expf(LRELU(a_src[s * 4 + myh] + adm));
        union { float2 f; __half2 h[2]; } uu;
        uu.f = *(const float2*)&h1[(size_t)s * 64 + l16 * 4];
        float2 lo = __half22float2(uu.h[0]), hi = __half22float2(uu.h[1]);
        A0 += e * lo.x; A1 += e * lo.y; A2 += e * hi.x; A3 += e * hi.y;
    }
    A0 += B0; A1 += B1; A2 += B2; A3 += B3;
    float4 bb = ((const float4*)bias)[l16];
    float o0 = A0 * iv + bb.x;
    float o1 = A1 * iv + bb.y;
    float o2 = A2 * iv + bb.z;
    float o3 = A3 * iv + bb.w;
    o0 = (o0 > 0.f) ? o0 : (__expf(o0) - 1.f);
    o1 = (o1 > 0.f) ? o1 : (__expf(o1) - 1.f);
    o2 = (o2 > 0.f) ? o2 : (__expf(o2) - 1.f);
    o3 = (o3 > 0.f) ? o3 : (__expf(o3) - 1.f);
    union { __half2 h2v[2]; float2 f2; } pk;
    pk.h2v[0] = __floats2half2_rn(o0, o1);
    pk.h2v[1] = __floats2half2_rn(o2, o3);
    *(float2*)&out1[(size_t)node * 64 + l16 * 4] = pk.f2;
}

// h2[N,16](fp16) = out1[N,64](fp16) @ W2[64,16] via MFMA f16; att2 via
// folded Wc2/Wd2 columns. 4 node-tiles per block.
__global__ __launch_bounds__(256) void k_gemm2(const __half* __restrict__ out1,
                                               const float* __restrict__ W2,
                                               const float* __restrict__ Wc2,
                                               __half* __restrict__ h2, float* __restrict__ a_src,
                                               float* __restrict__ a_dst, int N) {
    __shared__ _Float16 wt2[16][72];   // wt2[c][k] = W2[k][c]
    __shared__ _Float16 wtb[16][72];   // col0 = Wc2, col1 = Wd2, rest 0
    int tid = threadIdx.x;
    for (int i = tid; i < 16 * 64; i += 256) {
        int k = i >> 4, c = i & 15;
        wt2[c][k] = (_Float16)W2[i];
    }
    for (int i = tid; i < 16 * 64; i += 256) {
        int col = i >> 6, k = i & 63;
        wtb[col][k] = (col < 2) ? (_Float16)Wc2[col * 64 + k] : (_Float16)0.f;
    }
    __syncthreads();
    int wave = tid >> 6, lane = tid & 63;
    int m = lane & 15, q = lane >> 4;

    #pragma unroll
    for (int t = 0; t < 4; t++) {
        int nbase = blockIdx.x * 256 + t * 64 + wave * 16;
        if (nbase >= N) break;
        int anode = nbase + m;
        bool ok = anode < N;
        const __half* arow = out1 + (size_t)(ok ? anode : 0) * 64 + q * 8;

        float4v c1 = {0.f, 0.f, 0.f, 0.f}, c2v = {0.f, 0.f, 0.f, 0.f};
        #pragma unroll
        for (int kc = 0; kc < 2; kc++) {
            half8 af = *(const half8*)(arow + kc * 32);
            half8 b1 = *(const half8*)&wt2[m][kc * 32 + q * 8];
            half8 b2 = *(const half8*)&wtb[m][kc * 32 + q * 8];
            c1  = __builtin_amdgcn_mfma_f32_16x16x32_f16(af, b1, c1, 0, 0, 0);
            c2v = __builtin_amdgcn_mfma_f32_16x16x32_f16(af, b2, c2v, 0, 0, 0);
        }
        #pragma unroll
        for (int r = 0; r < 4; r++) {
            int n = nbase + q * 4 + r;
            if (n < N) {
                h2[(size_t)n * 16 + m] = __float2half(c1[r]);
                if (m == 0) a_src[n] = c2v[r];
                else if (m == 1) a_dst[n] = c2v[r];
            }
        }
    }
}

// layer-2 aggregation + bias + log_softmax; 4 nodes/wave, fp16 h2 gathers
__global__ __launch_bounds__(256) void k_agg2(const int* __restrict__ row_start,
                                              const int* __restrict__ csr_src,
                                              const float* __restrict__ a_src,
                                              const float* __restrict__ a_dst,
                                              const __half* __restrict__ h2,
                                              const float* __restrict__ bias,
                                              float* __restrict__ out, int N) {
    __shared__ int   sidx[16][CAP2];
    __shared__ float sval[16][CAP2];
    int tid = threadIdx.x;
    int wave = tid >> 6, lane = tid & 63;
    int quad = lane >> 4, l16 = lane & 15;
    int slot = wave * 4 + quad;
    int node = blockIdx.x * 16 + slot;
    if (node >= N) return;
    int row = row_start[node];
    int deg = row_start[node + 1] - row;
    float ad = a_dst[node];
    float sh = 0.f;
    for (int j = l16; j < deg; j += 16) {
        int s = csr_src[row + j];
        float e = __expf(LRELU(a_src[s] + ad));
        if (j < CAP2) { sidx[slot][j] = s; sval[slot][j] = e; }
        sh += e;
    }
    #pragma unroll
    for (int m = 1; m < 16; m <<= 1) sh += __shfl_xor(sh, m, 64);
    float iv = 1.f / (sh + 1e-16f);
    int cg = l16 & 7, eg = l16 >> 3;
    float ax = 0.f, ay = 0.f, bx = 0.f, by = 0.f;
    int dc = deg < CAP2 ? deg : CAP2;
    int j = eg;
    for (; j + 6 < dc; j += 8) {
        int t0 = sidx[slot][j], t1 = sidx[slot][j + 2];
        int t2 = sidx[slot][j + 4], t3 = sidx[slot][j + 6];
        float e0 = sval[slot][j], e1 = sval[slot][j + 2];
        float e2 = sval[slot][j + 4], e3 = sval[slot][j + 6];
        float2 g0 = __half22float2(*(const __half2*)&h2[(size_t)t0 * 16 + cg * 2]);
        float2 g1 = __half22float2(*(const __half2*)&h2[(size_t)t1 * 16 + cg * 2]);
        float2 g2 = __half22float2(*(const __half2*)&h2[(size_t)t2 * 16 + cg * 2]);
        float2 g3 = __half22float2(*(const __half2*)&h2[(size_t)t3 * 16 + cg * 2]);
        ax += e0 * g0.x + e2 * g2.x; ay += e0 * g0.y + e2 * g2.y;
        bx += e1 * g1.x + e3 * g3.x; by += e1 * g1.y + e3 * g3.y;
    }
    for (; j < deg; j += 2) {
        int s; float e;
        if (j < dc) { s = sidx[slot][j]; e = sval[slot][j]; }
        else { s = csr_src[row + j]; e = __expf(LRELU(a_src[s] + ad)); }
        float2 g = __half22float2(*(const __half2*)&h2[(size_t)s * 16 + cg * 2]);
        ax += e * g.x; ay += e * g.y;
    }
    ax += bx; ay += by;
    ax += __shfl_xor(ax, 8, 64);
    ay += __shfl_xor(ay, 8, 64);
    float2 bb = ((const float2*)bias)[cg];
    float vx = ax * iv + bb.x;
    float vy = ay * iv + bb.y;
    float mx = fmaxf(vx, vy);
    #pragma unroll
    for (int m = 1; m < 8; m <<= 1) mx = fmaxf(mx, __shfl_xor(mx, m, 64));
    float se = __expf(vx - mx) + __expf(vy - mx);
    #pragma unroll
    for (int m = 1; m < 8; m <<= 1) se += __shfl_xor(se, m, 64);
    float ls = mx + __logf(se);
    if (eg == 0)
        ((float2*)out)[(size_t)node * 8 + cg] = make_float2(vx - ls, vy - ls);
}

extern "C" void kernel_launch(void* const* d_in, const int* in_sizes, int n_in,
                              void* d_out, int out_size, void* d_ws, size_t ws_size,
                              hipStream_t stream) {
    const float* x        = (const float*)d_in[0];
    const int*   ei       = (const int*)d_in[1];
    const float* W1       = (const float*)d_in[2];
    const float* att_src1 = (const float*)d_in[3];
    const float* att_dst1 = (const float*)d_in[4];
    const float* bias1    = (const float*)d_in[5];
    const float* W2       = (const float*)d_in[6];
    const float* att_src2 = (const float*)d_in[7];
    const float* att_dst2 = (const float*)d_in[8];
    const float* bias2    = (const float*)d_in[9];
    float* out = (float*)d_out;

    const int N = in_sizes[0] / 128;
    const int E = in_sizes[1] / 2;
    const int NBK = (N + 255) >> BSH;

    char* p = (char*)d_ws;
    auto alloc = [&](size_t bytes) -> void* {
        void* r = (void*)p;
        p += (bytes + 255) & ~(size_t)255;
        return r;
    };
    __half* h1     = (__half*)alloc((size_t)N * 64 * 2);
    __half* out1   = (__half*)alloc((size_t)N * 64 * 2);
    __half* h2     = (__half*)alloc((size_t)N * 16 * 2);
    float* a_src1  = (float*)alloc((size_t)N * 4 * 4);
    float* a_dst1  = (float*)alloc((size_t)N * 4 * 4);
    float* a_src2  = (float*)alloc((size_t)N * 4);
    float* a_dst2  = (float*)alloc((size_t)N * 4);
    float* Wc      = (float*)alloc(16 * 128 * 4);
    float* Wc2     = (float*)alloc(2 * 64 * 4);
    int*   row_st  = (int*)alloc((size_t)(N + 1) * 4);
    int*   csr     = (int*)alloc((size_t)(E + N) * 4);
    int*   stage   = (int*)alloc((size_t)NBK * BCAP * 4);
    int*   cursor  = (int*)alloc((size_t)NBK * 4);
    (void)ws_size; (void)n_in; (void)out_size;

    hipMemsetAsync(cursor, 0, (size_t)NBK * 4, stream);
    k_scatter<<<(E + CHK - 1) / CHK, 256, 0, stream>>>(ei, cursor, stage, E, NBK);
    k_build<<<NBK, 256, 0, stream>>>(stage, cursor, row_st, csr,
                                     W1, att_src1, att_dst1, Wc,
                                     W2, att_src2, att_dst2, Wc2, NBK, E, N);
    k_gemm1<<<(N + 255) / 256, 256, 0, stream>>>(x, W1, Wc, h1, a_src1, a_dst1, N);
    k_agg1<<<(N + 15) / 16, 256, 0, stream>>>(row_st, csr, a_src1, a_dst1, h1, bias1, out1, N);
    k_gemm2<<<(N + 255) / 256, 256, 0, stream>>>(out1, W2, Wc2, h2, a_src2, a_dst2, N);
    k_agg2<<<(N + 15) / 16, 256, 0, stream>>>(row_st, csr, a_src2, a_dst2, h2, bias2, out, N);
}

// Round 15
// 237.901 us; speedup vs baseline: 1.0253x; 1.0253x over previous
//
#include <hip/hip_runtime.h>
#include <hip/hip_fp16.h>
#include <hip/hip_bf16.h>
#include <math.h>

// GAT 2-layer forward, MI355X. FP32 in/out, int32 edge_index.
// R15 = exact revert to R13 (measured 236.6us; R14's 4-tile gemm blocks
// dropped grid to 1.5 blocks/CU and regressed +7.4us).
// Structure: scan-free scatter, fused build (+Wc/Wc2 precompute in blk 0),
// MFMA gemm1 (bf16, folded att cols), 4-node/wave latency-optimized aggs,
// MFMA gemm2 (f16, folded att cols), fp16 intermediates everywhere.

#define LRELU(v) ((v) > 0.f ? (v) : 0.2f * (v))
#define BSH 8            // 256 nodes per bucket
#define BCAP 5120        // staged capacity per bucket
#define CHK 8192         // edges per k_scatter block
#define CAP1 64          // agg1 LDS edge cache per node
#define CAP2 64          // agg2 LDS edge cache per node

typedef __attribute__((ext_vector_type(8))) short short8;
typedef __attribute__((ext_vector_type(8))) _Float16 half8;
typedef __attribute__((ext_vector_type(4))) float float4v;

static __device__ __forceinline__ short f2bf(float f) {
    __hip_bfloat16 b = __float2bfloat16(f);
    return *reinterpret_cast<short*>(&b);
}

// Pass 1 (scan-free): histogram -> reserve per-bucket global runs -> direct
// writes into contiguous runs.
__global__ __launch_bounds__(256) void k_scatter(const int* __restrict__ ei, int* __restrict__ cursor,
                                                 int* __restrict__ stage, int E, int NBK) {
    __shared__ int hist[512];
    __shared__ int cnt2[512];
    __shared__ int base[512];
    int tid = threadIdx.x;
    int e0 = blockIdx.x * CHK;
    int nedge = E - e0; if (nedge > CHK) nedge = CHK;

    for (int i = tid; i < 512; i += 256) { hist[i] = 0; cnt2[i] = 0; }
    __syncthreads();
    for (int j = tid; j < nedge; j += 256) {
        int d = ei[E + e0 + j];
        atomicAdd(&hist[d >> BSH], 1);
    }
    __syncthreads();
    for (int b = tid; b < NBK; b += 256) {
        int c = hist[b];
        if (c > 0) base[b] = b * BCAP + atomicAdd(&cursor[b], c);
    }
    __syncthreads();
    for (int j = tid; j < nedge; j += 256) {
        int s = ei[e0 + j];
        int d = ei[E + e0 + j];
        int b = d >> BSH;
        int r = atomicAdd(&cnt2[b], 1);
        stage[base[b] + r] = s | ((d & ((1 << BSH) - 1)) << 17);
    }
}

// Pass 2: per-bucket fine CSR build. Block 0 also writes row_start[N],
// Wc (gemm1 att columns) and Wc2/Wd2 (gemm2 att columns).
__global__ __launch_bounds__(256) void k_build(const int* __restrict__ stage,
                                               const int* __restrict__ cursor,
                                               int* __restrict__ row_start,
                                               int* __restrict__ csr,
                                               const float* __restrict__ W1,
                                               const float* __restrict__ att_src,
                                               const float* __restrict__ att_dst,
                                               float* __restrict__ Wc,
                                               const float* __restrict__ W2,
                                               const float* __restrict__ att_src2,
                                               const float* __restrict__ att_dst2,
                                               float* __restrict__ Wc2,
                                               int NBK, int E, int N) {
    __shared__ int cnt[256];
    __shared__ int lb[256];
    __shared__ int cur[256];
    __shared__ int sA[256];
    int b = blockIdx.x, tid = threadIdx.x;
    int nodes0 = b << BSH;
    int nnodes = N - nodes0; if (nnodes > 256) nnodes = 256;
    int partial = 0;
    for (int i = tid; i < b; i += 256) partial += cursor[i];
    sA[tid] = partial;
    __syncthreads();
    for (int off = 128; off >= 1; off >>= 1) {
        if (tid < off) sA[tid] += sA[tid + off];
        __syncthreads();
    }
    int ebase = sA[0];
    int ecnt = cursor[b];
    __syncthreads();
    if (b == 0) {
        if (tid == 0) row_start[N] = E + N;
        for (int i = tid; i < 16 * 128; i += 256) {
            int col = i >> 7, k = i & 127;
            float v = 0.f;
            if (col < 8) {
                int h = col & 3;
                const float* att = (col < 4) ? att_src : att_dst;
                #pragma unroll
                for (int c = 0; c < 16; c++) v += W1[k * 64 + h * 16 + c] * att[h * 16 + c];
            }
            Wc[i] = v;
        }
        // Wc2: col0 = W2@att_src2 (64), col1 = W2@att_dst2 (64)
        for (int i = tid; i < 128; i += 256) {
            int col = i >> 6, k = i & 63;
            const float* att = col ? att_dst2 : att_src2;
            float v = 0.f;
            #pragma unroll
            for (int c = 0; c < 16; c++) v += W2[k * 16 + c] * att[c];
            Wc2[i] = v;
        }
    }
    const int* sbk = stage + b * BCAP;
    cnt[tid] = (tid < nnodes) ? 1 : 0;  // self loop
    __syncthreads();
    for (int e = tid; e < ecnt; e += 256) {
        int l = (sbk[e] >> 17) & 255;
        atomicAdd(&cnt[l], 1);
    }
    __syncthreads();
    int myc = cnt[tid];
    sA[tid] = myc;
    __syncthreads();
    for (int off = 1; off < 256; off <<= 1) {
        int r = sA[tid] + ((tid >= off) ? sA[tid - off] : 0);
        __syncthreads();
        sA[tid] = r;
        __syncthreads();
    }
    int gb = ebase + nodes0;
    lb[tid] = sA[tid] - myc;
    cur[tid] = 1;
    __syncthreads();
    if (tid < nnodes) {
        row_start[nodes0 + tid] = gb + lb[tid];
        csr[gb + lb[tid]] = nodes0 + tid;
    }
    __syncthreads();
    for (int e = tid; e < ecnt; e += 256) {
        int v = sbk[e];
        int l = (v >> 17) & 255;
        int src = v & 0x1FFFF;
        int r = atomicAdd(&cur[l], 1);
        csr[gb + lb[l] + r] = src;
    }
}

// h1[N,64](fp16) = x[N,128] @ W1[128,64] via MFMA 16x16x32 bf16.
__global__ __launch_bounds__(256) void k_gemm1(const float* __restrict__ x,
                                               const float* __restrict__ W1,
                                               const float* __restrict__ Wc,
                                               __half* __restrict__ h1, float* __restrict__ a_src,
                                               float* __restrict__ a_dst, int N) {
    __shared__ short wt[80 * 136];   // cols 0-63: W1^T; cols 64-79: Wc
    int tid = threadIdx.x;
    for (int i = tid; i < 128 * 64; i += 256) {
        int k = i >> 6, c = i & 63;
        wt[c * 136 + k] = f2bf(W1[i]);
    }
    for (int i = tid; i < 16 * 128; i += 256) {
        int col = i >> 7, k = i & 127;
        wt[(64 + col) * 136 + k] = f2bf(Wc[i]);
    }
    __syncthreads();
    int wave = tid >> 6, lane = tid & 63;
    int m = lane & 15, q = lane >> 4;
    int nbase = blockIdx.x * 64 + wave * 16;
    int anode = nbase + m;
    bool rowok = anode < N;
    const float* xrow = x + (size_t)(rowok ? anode : 0) * 128 + q * 8;

    float4v acc[5];
    #pragma unroll
    for (int ct = 0; ct < 5; ct++)
        #pragma unroll
        for (int r = 0; r < 4; r++) acc[ct][r] = 0.f;

    #pragma unroll
    for (int kc = 0; kc < 4; kc++) {
        float4 u0 = make_float4(0.f, 0.f, 0.f, 0.f), u1 = u0;
        if (rowok) {
            u0 = *(const float4*)(xrow + kc * 32);
            u1 = *(const float4*)(xrow + kc * 32 + 4);
        }
        short8 af;
        af[0] = f2bf(u0.x); af[1] = f2bf(u0.y); af[2] = f2bf(u0.z); af[3] = f2bf(u0.w);
        af[4] = f2bf(u1.x); af[5] = f2bf(u1.y); af[6] = f2bf(u1.z); af[7] = f2bf(u1.w);
        #pragma unroll
        for (int ct = 0; ct < 5; ct++) {
            short8 bf = *(const short8*)&wt[(ct * 16 + m) * 136 + kc * 32 + q * 8];
            acc[ct] = __builtin_amdgcn_mfma_f32_16x16x32_bf16(af, bf, acc[ct], 0, 0, 0);
        }
    }
    #pragma unroll
    for (int ct = 0; ct < 4; ct++) {
        #pragma unroll
        for (int r = 0; r < 4; r++) {
            int n = nbase + q * 4 + r;
            if (n < N) h1[(size_t)n * 64 + ct * 16 + m] = __float2half(acc[ct][r]);
        }
    }
    #pragma unroll
    for (int r = 0; r < 4; r++) {
        int n = nbase + q * 4 + r;
        if (n < N) {
            float v = acc[4][r];
            if (m < 4) a_src[n * 4 + m] = v;
            else if (m < 8) a_dst[n * 4 + (m - 4)] = v;
        }
    }
}

// layer-1 aggregation: 4 nodes per wave (16 lanes x 4 channels); out1 fp16
__global__ __launch_bounds__(256) void k_agg1(const int* __restrict__ row_start,
                                              const int* __restrict__ csr_src,
                                              const float* __restrict__ a_src,
                                              const float* __restrict__ a_dst,
                                              const __half* __restrict__ h1,
                                              const float* __restrict__ bias,
                                              __half* __restrict__ out1, int N) {
    __shared__ int   sidx[16][CAP1];
    __shared__ float sval[16][CAP1 * 4];
    int tid = threadIdx.x;
    int wave = tid >> 6, lane = tid & 63;
    int quad = lane >> 4, l16 = lane & 15;
    int slot = wave * 4 + quad;
    int node = blockIdx.x * 16 + slot;
    if (node >= N) return;
    int row = row_start[node];
    int deg = row_start[node + 1] - row;
    float4 ad = ((const float4*)a_dst)[node];
    float s0 = 0.f, s1 = 0.f, s2 = 0.f, s3 = 0.f;
    for (int j = l16; j < deg; j += 16) {
        int s = csr_src[row + j];
        float4 as = ((const float4*)a_src)[s];
        float e0 = __expf(LRELU(as.x + ad.x));
        float e1 = __expf(LRELU(as.y + ad.y));
        float e2 = __expf(LRELU(as.z + ad.z));
        float e3 = __expf(LRELU(as.w + ad.w));
        if (j < CAP1) {
            sidx[slot][j] = s;
            *(float4*)&sval[slot][j * 4] = make_float4(e0, e1, e2, e3);
        }
        s0 += e0; s1 += e1; s2 += e2; s3 += e3;
    }
    #pragma unroll
    for (int m = 1; m < 16; m <<= 1) {
        s0 += __shfl_xor(s0, m, 64);
        s1 += __shfl_xor(s1, m, 64);
        s2 += __shfl_xor(s2, m, 64);
        s3 += __shfl_xor(s3, m, 64);
    }
    int myh = l16 >> 2;
    float ssv = myh == 0 ? s0 : myh == 1 ? s1 : myh == 2 ? s2 : s3;
    float adm = myh == 0 ? ad.x : myh == 1 ? ad.y : myh == 2 ? ad.z : ad.w;
    float iv = 1.f / (ssv + 1e-16f);
    float A0 = 0.f, A1 = 0.f, A2 = 0.f, A3 = 0.f;
    float B0 = 0.f, B1 = 0.f, B2 = 0.f, B3 = 0.f;
    int dc = deg < CAP1 ? deg : CAP1;
    int j = 0;
    for (; j + 8 <= dc; j += 8) {
        int t[8]; float e[8]; float2 lo[8], hi[8];
        #pragma unroll
        for (int u = 0; u < 8; u++) {
            t[u] = sidx[slot][j + u];
            e[u] = sval[slot][(j + u) * 4 + myh];
        }
        #pragma unroll
        for (int u = 0; u < 8; u++) {
            union { float2 f; __half2 h[2]; } uu;
            uu.f = *(const float2*)&h1[(size_t)t[u] * 64 + l16 * 4];
            lo[u] = __half22float2(uu.h[0]);
            hi[u] = __half22float2(uu.h[1]);
        }
        #pragma unroll
        for (int u = 0; u < 8; u += 2) {
            A0 += e[u] * lo[u].x; A1 += e[u] * lo[u].y;
            A2 += e[u] * hi[u].x; A3 += e[u] * hi[u].y;
            B0 += e[u + 1] * lo[u + 1].x; B1 += e[u + 1] * lo[u + 1].y;
            B2 += e[u + 1] * hi[u + 1].x; B3 += e[u + 1] * hi[u + 1].y;
        }
    }
    for (; j < dc; j++) {
        int t = sidx[slot][j];
        float e = sval[slot][j * 4 + myh];
        union { float2 f; __half2 h[2]; } uu;
        uu.f = *(const float2*)&h1[(size_t)t * 64 + l16 * 4];
        float2 lo = __half22float2(uu.h[0]), hi = __half22float2(uu.h[1]);
        A0 += e * lo.x; A1 += e * lo.y; A2 += e * hi.x; A3 += e * hi.y;
    }
    for (; j < deg; j++) {   // deg > CAP1 fallback
        int s = csr_src[row + j];
        float e = __expf(LRELU(a_src[s * 4 + myh] + adm));
        union { float2 f; __half2 h[2]; } uu;
        uu.f = *(const float2*)&h1[(size_t)s * 64 + l16 * 4];
        float2 lo = __half22float2(uu.h[0]), hi = __half22float2(uu.h[1]);
        A0 += e * lo.x; A1 += e * lo.y; A2 += e * hi.x; A3 += e * hi.y;
    }
    A0 += B0; A1 += B1; A2 += B2; A3 += B3;
    float4 bb = ((const float4*)bias)[l16];
    float o0 = A0 * iv + bb.x;
    float o1 = A1 * iv + bb.y;
    float o2 = A2 * iv + bb.z;
    float o3 = A3 * iv + bb.w;
    o0 = (o0 > 0.f) ? o0 : (__expf(o0) - 1.f);
    o1 = (o1 > 0.f) ? o1 : (__expf(o1) - 1.f);
    o2 = (o2 > 0.f) ? o2 : (__expf(o2) - 1.f);
    o3 = (o3 > 0.f) ? o3 : (__expf(o3) - 1.f);
    union { __half2 h2v[2]; float2 f2; } pk;
    pk.h2v[0] = __floats2half2_rn(o0, o1);
    pk.h2v[1] = __floats2half2_rn(o2, o3);
    *(float2*)&out1[(size_t)node * 64 + l16 * 4] = pk.f2;
}

// h2[N,16](fp16) = out1[N,64](fp16) @ W2[64,16] via MFMA f16; att2 dots
// via folded Wc2/Wd2 columns (2nd B-frag) — shuffle-free epilogue.
__global__ __launch_bounds__(256) void k_gemm2(const __half* __restrict__ out1,
                                               const float* __restrict__ W2,
                                               const float* __restrict__ Wc2,
                                               __half* __restrict__ h2, float* __restrict__ a_src,
                                               float* __restrict__ a_dst, int N) {
    __shared__ _Float16 wt2[16][72];   // wt2[c][k] = W2[k][c]
    __shared__ _Float16 wtb[16][72];   // col0 = Wc2, col1 = Wd2, rest 0
    int tid = threadIdx.x;
    for (int i = tid; i < 16 * 64; i += 256) {
        int k = i >> 4, c = i & 15;
        wt2[c][k] = (_Float16)W2[i];
    }
    for (int i = tid; i < 16 * 64; i += 256) {
        int col = i >> 6, k = i & 63;
        wtb[col][k] = (col < 2) ? (_Float16)Wc2[col * 64 + k] : (_Float16)0.f;
    }
    __syncthreads();
    int wave = tid >> 6, lane = tid & 63;
    int m = lane & 15, q = lane >> 4;
    int nbase = blockIdx.x * 64 + wave * 16;
    int anode = nbase + m;
    bool ok = anode < N;
    const __half* arow = out1 + (size_t)(ok ? anode : 0) * 64 + q * 8;

    float4v c1 = {0.f, 0.f, 0.f, 0.f}, c2v = {0.f, 0.f, 0.f, 0.f};
    #pragma unroll
    for (int kc = 0; kc < 2; kc++) {
        half8 af = *(const half8*)(arow + kc * 32);
        half8 b1 = *(const half8*)&wt2[m][kc * 32 + q * 8];
        half8 b2 = *(const half8*)&wtb[m][kc * 32 + q * 8];
        c1  = __builtin_amdgcn_mfma_f32_16x16x32_f16(af, b1, c1, 0, 0, 0);
        c2v = __builtin_amdgcn_mfma_f32_16x16x32_f16(af, b2, c2v, 0, 0, 0);
    }
    #pragma unroll
    for (int r = 0; r < 4; r++) {
        int n = nbase + q * 4 + r;
        if (n < N) {
            h2[(size_t)n * 16 + m] = __float2half(c1[r]);
            if (m == 0) a_src[n] = c2v[r];
            else if (m == 1) a_dst[n] = c2v[r];
        }
    }
}

// layer-2 aggregation + bias + log_softmax; 4 nodes/wave, fp16 h2 gathers
__global__ __launch_bounds__(256) void k_agg2(const int* __restrict__ row_start,
                                              const int* __restrict__ csr_src,
                                              const float* __restrict__ a_src,
                                              const float* __restrict__ a_dst,
                                              const __half* __restrict__ h2,
                                              const float* __restrict__ bias,
                                              float* __restrict__ out, int N) {
    __shared__ int   sidx[16][CAP2];
    __shared__ float sval[16][CAP2];
    int tid = threadIdx.x;
    int wave = tid >> 6, lane = tid & 63;
    int quad = lane >> 4, l16 = lane & 15;
    int slot = wave * 4 + quad;
    int node = blockIdx.x * 16 + slot;
    if (node >= N) return;
    int row = row_start[node];
    int deg = row_start[node + 1] - row;
    float ad = a_dst[node];
    float sh = 0.f;
    for (int j = l16; j < deg; j += 16) {
        int s = csr_src[row + j];
        float e = __expf(LRELU(a_src[s] + ad));
        if (j < CAP2) { sidx[slot][j] = s; sval[slot][j] = e; }
        sh += e;
    }
    #pragma unroll
    for (int m = 1; m < 16; m <<= 1) sh += __shfl_xor(sh, m, 64);
    float iv = 1.f / (sh + 1e-16f);
    int cg = l16 & 7, eg = l16 >> 3;
    float ax = 0.f, ay = 0.f, bx = 0.f, by = 0.f;
    int dc = deg < CAP2 ? deg : CAP2;
    int j = eg;
    for (; j + 6 < dc; j += 8) {
        int t0 = sidx[slot][j], t1 = sidx[slot][j + 2];
        int t2 = sidx[slot][j + 4], t3 = sidx[slot][j + 6];
        float e0 = sval[slot][j], e1 = sval[slot][j + 2];
        float e2 = sval[slot][j + 4], e3 = sval[slot][j + 6];
        float2 g0 = __half22float2(*(const __half2*)&h2[(size_t)t0 * 16 + cg * 2]);
        float2 g1 = __half22float2(*(const __half2*)&h2[(size_t)t1 * 16 + cg * 2]);
        float2 g2 = __half22float2(*(const __half2*)&h2[(size_t)t2 * 16 + cg * 2]);
        float2 g3 = __half22float2(*(const __half2*)&h2[(size_t)t3 * 16 + cg * 2]);
        ax += e0 * g0.x + e2 * g2.x; ay += e0 * g0.y + e2 * g2.y;
        bx += e1 * g1.x + e3 * g3.x; by += e1 * g1.y + e3 * g3.y;
    }
    for (; j < deg; j += 2) {
        int s; float e;
        if (j < dc) { s = sidx[slot][j]; e = sval[slot][j]; }
        else { s = csr_src[row + j]; e = __expf(LRELU(a_src[s] + ad)); }
        float2 g = __half22float2(*(const __half2*)&h2[(size_t)s * 16 + cg * 2]);
        ax += e * g.x; ay += e * g.y;
    }
    ax += bx; ay += by;
    ax += __shfl_xor(ax, 8, 64);
    ay += __shfl_xor(ay, 8, 64);
    float2 bb = ((const float2*)bias)[cg];
    float vx = ax * iv + bb.x;
    float vy = ay * iv + bb.y;
    float mx = fmaxf(vx, vy);
    #pragma unroll
    for (int m = 1; m < 8; m <<= 1) mx = fmaxf(mx, __shfl_xor(mx, m, 64));
    float se = __expf(vx - mx) + __expf(vy - mx);
    #pragma unroll
    for (int m = 1; m < 8; m <<= 1) se += __shfl_xor(se, m, 64);
    float ls = mx + __logf(se);
    if (eg == 0)
        ((float2*)out)[(size_t)node * 8 + cg] = make_float2(vx - ls, vy - ls);
}

extern "C" void kernel_launch(void* const* d_in, const int* in_sizes, int n_in,
                              void* d_out, int out_size, void* d_ws, size_t ws_size,
                              hipStream_t stream) {
    const float* x        = (const float*)d_in[0];
    const int*   ei       = (const int*)d_in[1];
    const float* W1       = (const float*)d_in[2];
    const float* att_src1 = (const float*)d_in[3];
    const float* att_dst1 = (const float*)d_in[4];
    const float* bias1    = (const float*)d_in[5];
    const float* W2       = (const float*)d_in[6];
    const float* att_src2 = (const float*)d_in[7];
    const float* att_dst2 = (const float*)d_in[8];
    const float* bias2    = (const float*)d_in[9];
    float* out = (float*)d_out;

    const int N = in_sizes[0] / 128;
    const int E = in_sizes[1] / 2;
    const int NBK = (N + 255) >> BSH;

    char* p = (char*)d_ws;
    auto alloc = [&](size_t bytes) -> void* {
        void* r = (void*)p;
        p += (bytes + 255) & ~(size_t)255;
        return r;
    };
    __half* h1     = (__half*)alloc((size_t)N * 64 * 2);
    __half* out1   = (__half*)alloc((size_t)N * 64 * 2);
    __half* h2     = (__half*)alloc((size_t)N * 16 * 2);
    float* a_src1  = (float*)alloc((size_t)N * 4 * 4);
    float* a_dst1  = (float*)alloc((size_t)N * 4 * 4);
    float* a_src2  = (float*)alloc((size_t)N * 4);
    float* a_dst2  = (float*)alloc((size_t)N * 4);
    float* Wc      = (float*)alloc(16 * 128 * 4);
    float* Wc2     = (float*)alloc(2 * 64 * 4);
    int*   row_st  = (int*)alloc((size_t)(N + 1) * 4);
    int*   csr     = (int*)alloc((size_t)(E + N) * 4);
    int*   stage   = (int*)alloc((size_t)NBK * BCAP * 4);
    int*   cursor  = (int*)alloc((size_t)NBK * 4);
    (void)ws_size; (void)n_in; (void)out_size;

    hipMemsetAsync(cursor, 0, (size_t)NBK * 4, stream);
    k_scatter<<<(E + CHK - 1) / CHK, 256, 0, stream>>>(ei, cursor, stage, E, NBK);
    k_build<<<NBK, 256, 0, stream>>>(stage, cursor, row_st, csr,
                                     W1, att_src1, att_dst1, Wc,
                                     W2, att_src2, att_dst2, Wc2, NBK, E, N);
    k_gemm1<<<(N + 63) / 64, 256, 0, stream>>>(x, W1, Wc, h1, a_src1, a_dst1, N);
    k_agg1<<<(N + 15) / 16, 256, 0, stream>>>(row_st, csr, a_src1, a_dst1, h1, bias1, out1, N);
    k_gemm2<<<(N + 63) / 64, 256, 0, stream>>>(out1, W2, Wc2, h2, a_src2, a_dst2, N);
    k_agg2<<<(N + 15) / 16, 256, 0, stream>>>(row_st, csr, a_src2, a_dst2, h2, bias2, out, N);
}